// Round 1
// baseline (195.404 us; speedup 1.0000x reference)
//
#include <hip/hip_runtime.h>
#include <hip/hip_bf16.h>

#define NN 16384
#define DD 128
#define BM 128
#define BN 128

typedef __attribute__((ext_vector_type(8))) short bf16x8;
typedef __attribute__((ext_vector_type(4))) float f32x4;

// exp(dot/T) = exp2(dot * log2(e)/T), T = 0.07
#define EXP_SCALE 20.6099291555f

// ---------------- Kernel 1: fp32 -> bf16 convert, pre-swizzled global layout ---
// 16B chunk c (8 bf16) of row r is stored at chunk position (c ^ (r&7)).
// Then a linear global->LDS copy produces the XOR-swizzled LDS tile for free.
__global__ void convert_swz(const float* __restrict__ x, ushort* __restrict__ xb) {
    int t = blockIdx.x * blockDim.x + threadIdx.x;   // one thread per 8-elem chunk
    int r = t >> 4;          // row
    int c = t & 15;          // chunk within row (16 chunks of 8 elems)
    const float4* src = (const float4*)(x + (size_t)r * DD + c * 8);
    float4 f0 = src[0];
    float4 f1 = src[1];
    float vals[8] = {f0.x, f0.y, f0.z, f0.w, f1.x, f1.y, f1.z, f1.w};
    bf16x8 v;
#pragma unroll
    for (int i = 0; i < 8; ++i) {
        __hip_bfloat16 h = __float2bfloat16(vals[i]);
        v[i] = (short)__builtin_bit_cast(unsigned short, h);
    }
    int cs = c ^ (r & 7);
    *(bf16x8*)(xb + (size_t)r * DD + cs * 8) = v;
}

// ---------------- Kernel 2: tiled X·X^T -> exp -> row-sum ----------------------
// Grid (128,128): block computes 128x128 tile of sims, adds exp() row sums
// into rowsum[] via atomics. 4 waves in 2x2 layout, 64x64 per wave.
__global__ __launch_bounds__(256, 2) void gemm_exp(const ushort* __restrict__ xb,
                                                   float* __restrict__ rowsum) {
    __shared__ __align__(16) ushort lA[BM * DD];  // 32 KB, swizzled layout
    __shared__ __align__(16) ushort lB[BN * DD];  // 32 KB

    const int tid  = threadIdx.x;
    const int lane = tid & 63;
    const int wid  = tid >> 6;
    const int rt   = blockIdx.x;
    const int ct   = blockIdx.y;

    const char* gA = (const char*)(xb + (size_t)rt * BM * DD);
    const char* gB = (const char*)(xb + (size_t)ct * BN * DD);

    // Stage both 32KB tiles: full K=128 row => tile is contiguous in xb.
    // Each wave stages 8x 1KB chunks per tile (lane*16 added by HW on LDS side).
#pragma unroll
    for (int i = 0; i < 8; ++i) {
        int off = (wid * 8 + i) * 1024;
        __builtin_amdgcn_global_load_lds(
            (const __attribute__((address_space(1))) unsigned int*)(gA + off + lane * 16),
            (__attribute__((address_space(3))) unsigned int*)((char*)lA + off),
            16, 0, 0);
        __builtin_amdgcn_global_load_lds(
            (const __attribute__((address_space(1))) unsigned int*)(gB + off + lane * 16),
            (__attribute__((address_space(3))) unsigned int*)((char*)lB + off),
            16, 0, 0);
    }
    __syncthreads();

    const int wm   = wid >> 1;      // wave row (0..1)
    const int wn   = wid & 1;       // wave col (0..1)
    const int frow = lane & 15;     // fragment row/col within 16
    const int kq   = lane >> 4;     // k-quarter (0..3)

    f32x4 acc[4][4] = {};

#pragma unroll
    for (int kk = 0; kk < 4; ++kk) {            // K steps of 32
        const int chunk = kk * 4 + kq;          // 8-elem chunk index in row
        bf16x8 af[4], bfr[4];
#pragma unroll
        for (int m = 0; m < 4; ++m) {
            int r = wm * 64 + m * 16 + frow;
            int cidx = chunk ^ (r & 7);
            af[m] = *(const bf16x8*)&lA[r * DD + cidx * 8];
        }
#pragma unroll
        for (int n = 0; n < 4; ++n) {
            int r = wn * 64 + n * 16 + frow;
            int cidx = chunk ^ (r & 7);
            bfr[n] = *(const bf16x8*)&lB[r * DD + cidx * 8];
        }
#pragma unroll
        for (int m = 0; m < 4; ++m)
#pragma unroll
            for (int n = 0; n < 4; ++n)
                acc[m][n] = __builtin_amdgcn_mfma_f32_16x16x32_bf16(af[m], bfr[n],
                                                                    acc[m][n], 0, 0, 0);
    }

    // Epilogue: p = exp2(dot*SCALE); sum over this wave's 64 cols per row.
    // C/D layout: col = lane&15, row = (lane>>4)*4 + reg  (m89/m91 verified).
    float rs[4][4];
#pragma unroll
    for (int m = 0; m < 4; ++m) {
#pragma unroll
        for (int j = 0; j < 4; ++j) {
            float s = 0.f;
#pragma unroll
            for (int n = 0; n < 4; ++n)
                s += exp2f(acc[m][n][j] * EXP_SCALE);
            // reduce across the 16 col-lanes
            s += __shfl_xor(s, 1);
            s += __shfl_xor(s, 2);
            s += __shfl_xor(s, 4);
            s += __shfl_xor(s, 8);
            rs[m][j] = s;
        }
    }
    if (frow == 0) {
        int rowbase = rt * BM + wm * 64 + kq * 4;
#pragma unroll
        for (int m = 0; m < 4; ++m)
#pragma unroll
            for (int j = 0; j < 4; ++j)
                atomicAdd(&rowsum[rowbase + m * 16 + j], rs[m][j]);
    }
}

// ---------------- Kernel 3: mean(log(rowsum)) ---------------------------------
__global__ void finalize(const float* __restrict__ rowsum, float* __restrict__ out) {
    float s = 0.f;
    for (int i = threadIdx.x; i < NN; i += 256)
        s += logf(rowsum[i]);
#pragma unroll
    for (int o = 1; o < 64; o <<= 1)
        s += __shfl_xor(s, o);
    __shared__ float wsum[4];
    if ((threadIdx.x & 63) == 0) wsum[threadIdx.x >> 6] = s;
    __syncthreads();
    if (threadIdx.x == 0)
        out[0] = (wsum[0] + wsum[1] + wsum[2] + wsum[3]) * (1.0f / NN);
}

extern "C" void kernel_launch(void* const* d_in, const int* in_sizes, int n_in,
                              void* d_out, int out_size, void* d_ws, size_t ws_size,
                              hipStream_t stream) {
    const float* x = (const float*)d_in[0];
    float* out = (float*)d_out;

    ushort* xb    = (ushort*)d_ws;                               // 4 MB bf16, swizzled
    float* rowsum = (float*)((char*)d_ws + (size_t)NN * DD * 2); // 64 KB

    hipMemsetAsync(rowsum, 0, NN * sizeof(float), stream);
    convert_swz<<<(NN * 16) / 256, 256, 0, stream>>>(x, xb);
    gemm_exp<<<dim3(NN / BM, NN / BN), 256, 0, stream>>>(xb, rowsum);
    finalize<<<1, 256, 0, stream>>>(rowsum, out);
}

// Round 2
// 176.617 us; speedup vs baseline: 1.1064x; 1.1064x over previous
//
#include <hip/hip_runtime.h>
#include <hip/hip_bf16.h>

#define NN 16384
#define DD 128
#define TILE 256
#define NT (NN / TILE)             // 64 strips
#define NBLK (NT * (NT + 1) / 2)   // 2080 triangular tiles

typedef __attribute__((ext_vector_type(8))) short bf16x8;
typedef __attribute__((ext_vector_type(4))) float f32x4;

// exp(dot/T) = exp2(dot * log2(e)/T), T = 0.07
#define EXP_SCALE 20.6099291555f

// ---------------- Kernel 1: fp32 -> bf16 convert, pre-swizzled global layout ---
// 16B chunk c (8 bf16) of row r stored at chunk position (c ^ (r&7)), so a
// linear global->LDS copy yields the XOR-swizzled (bank-conflict-free) tile.
__global__ void convert_swz(const float* __restrict__ x, ushort* __restrict__ xb) {
    int t = blockIdx.x * blockDim.x + threadIdx.x;   // one thread per 8-elem chunk
    int r = t >> 4;
    int c = t & 15;
    const float4* src = (const float4*)(x + (size_t)r * DD + c * 8);
    float4 f0 = src[0];
    float4 f1 = src[1];
    float vals[8] = {f0.x, f0.y, f0.z, f0.w, f1.x, f1.y, f1.z, f1.w};
    bf16x8 v;
#pragma unroll
    for (int i = 0; i < 8; ++i) {
        __hip_bfloat16 h = __float2bfloat16(vals[i]);
        v[i] = (short)__builtin_bit_cast(unsigned short, h);
    }
    int cs = c ^ (r & 7);
    *(bf16x8*)(xb + (size_t)r * DD + cs * 8) = v;
}

// ---------------- Kernel 2: triangular tiled X·X^T -> exp -> row+col sums -----
// One block = one 256x256 triangular tile (ct >= rt). 8 waves (4x2), each wave
// computes 64 rows x 64 cols per 128-col half. B processed as two 128-col
// halves, prefetched with counted vmcnt so half1's loads fly during half0.
__global__ __launch_bounds__(512, 2) void gemm_exp_sym(const ushort* __restrict__ xb,
                                                       float* __restrict__ rowsum) {
    __shared__ __align__(16) ushort lA[TILE * DD];       // 64 KB
    __shared__ __align__(16) ushort lB[2][128 * DD];     // 2 x 32 KB

    const int tid  = threadIdx.x;
    const int lane = tid & 63;
    const int wid  = tid >> 6;       // 0..7
    const int frow = lane & 15;
    const int kq   = lane >> 4;

    // XCD-aware swizzle (2080 = 8*260, bijective), then triangular unrank.
    int bid = blockIdx.x;
    int i = (bid & 7) * (NBLK / 8) + (bid >> 3);
    // row rt has (NT - rt) tiles; tiles before row r: C(r) = (129r - r^2)/2
    int rt = (int)((129.0f - sqrtf(129.0f * 129.0f - 8.0f * (float)i)) * 0.5f);
    while ((129 * (rt + 1) - (rt + 1) * (rt + 1)) / 2 <= i) ++rt;
    while ((129 * rt - rt * rt) / 2 > i) --rt;
    const int ct = rt + (i - (129 * rt - rt * rt) / 2);

    const char* gA = (const char*)(xb + (size_t)rt * TILE * DD);
    const char* gB = (const char*)(xb + (size_t)ct * TILE * DD);

    // Issue all staging: A (8 gll/wave), B0 (4), B1 (4). Each gll moves 1 KB.
#pragma unroll
    for (int j = 0; j < 8; ++j) {
        int off = (wid * 8 + j) * 1024;
        __builtin_amdgcn_global_load_lds(
            (const __attribute__((address_space(1))) unsigned int*)(gA + off + lane * 16),
            (__attribute__((address_space(3))) unsigned int*)((char*)lA + off), 16, 0, 0);
    }
#pragma unroll
    for (int h = 0; h < 2; ++h)
#pragma unroll
        for (int j = 0; j < 4; ++j) {
            int off = (wid * 4 + j) * 1024;
            __builtin_amdgcn_global_load_lds(
                (const __attribute__((address_space(1))) unsigned int*)(gB + h * 32768 + off + lane * 16),
                (__attribute__((address_space(3))) unsigned int*)((char*)lB[h] + off), 16, 0, 0);
        }

    // Wait for A + B0 only (leave B1's 4 loads in flight).
    asm volatile("s_waitcnt vmcnt(4)" ::: "memory");
    __builtin_amdgcn_s_barrier();

    const int wm = wid >> 1;          // 0..3 -> 64-row slice
    const int wn = wid & 1;           // 0..1 -> 64-col slice within 128-col half
    const int rbase = wm * 64;
    const int cbase = wn * 64;

#pragma unroll
    for (int h = 0; h < 2; ++h) {
        if (h == 1) {
            asm volatile("s_waitcnt vmcnt(0)" ::: "memory");
            __builtin_amdgcn_s_barrier();
            __builtin_amdgcn_sched_barrier(0);
        }
        f32x4 acc[4][4];
#pragma unroll
        for (int m = 0; m < 4; ++m)
#pragma unroll
            for (int n = 0; n < 4; ++n)
                acc[m][n] = (f32x4){0.f, 0.f, 0.f, 0.f};

        const ushort* lBh = lB[h];
#pragma unroll
        for (int kk = 0; kk < 4; ++kk) {
            const int chunk = kk * 4 + kq;
            bf16x8 af[4], bfr[4];
#pragma unroll
            for (int m = 0; m < 4; ++m) {
                int ra = rbase + m * 16 + frow;
                int ca = chunk ^ (ra & 7);
                af[m] = *(const bf16x8*)&lA[ra * DD + ca * 8];
            }
#pragma unroll
            for (int n = 0; n < 4; ++n) {
                int rb = cbase + n * 16 + frow;
                int cb = chunk ^ (rb & 7);
                bfr[n] = *(const bf16x8*)&lBh[rb * DD + cb * 8];
            }
#pragma unroll
            for (int m = 0; m < 4; ++m)
#pragma unroll
                for (int n = 0; n < 4; ++n)
                    acc[m][n] = __builtin_amdgcn_mfma_f32_16x16x32_bf16(af[m], bfr[n],
                                                                        acc[m][n], 0, 0, 0);
        }

        // ---- epilogue: exp in place, then row-sums (+ col-sums if off-diag) --
        // C/D layout: col = frow, row = kq*4 + j  (per 16x16 fragment)
#pragma unroll
        for (int m = 0; m < 4; ++m)
#pragma unroll
            for (int n = 0; n < 4; ++n)
#pragma unroll
                for (int j = 0; j < 4; ++j)
                    acc[m][n][j] = __builtin_amdgcn_exp2f(acc[m][n][j] * EXP_SCALE);

        // row sums: reduce over n-frags + 16 col-lanes
        float rs[4][4];
#pragma unroll
        for (int m = 0; m < 4; ++m)
#pragma unroll
            for (int j = 0; j < 4; ++j) {
                float s = acc[m][0][j] + acc[m][1][j] + acc[m][2][j] + acc[m][3][j];
                s += __shfl_xor(s, 1);
                s += __shfl_xor(s, 2);
                s += __shfl_xor(s, 4);
                s += __shfl_xor(s, 8);
                rs[m][j] = s;
            }
        if (frow == 0) {
            int rowg = rt * TILE + rbase + kq * 4;
#pragma unroll
            for (int m = 0; m < 4; ++m)
#pragma unroll
                for (int j = 0; j < 4; ++j)
                    atomicAdd(&rowsum[rowg + m * 16 + j], rs[m][j]);
        }

        if (rt != ct) {
            // col sums: reduce over m-frags + regs + the 4 kq lane-groups
#pragma unroll
            for (int n = 0; n < 4; ++n) {
                float s = 0.f;
#pragma unroll
                for (int m = 0; m < 4; ++m)
#pragma unroll
                    for (int j = 0; j < 4; ++j)
                        s += acc[m][n][j];
                s += __shfl_xor(s, 16);
                s += __shfl_xor(s, 32);
                if (kq == 0)
                    atomicAdd(&rowsum[ct * TILE + h * 128 + cbase + n * 16 + frow], s);
            }
        }
    }
}

// ---------------- Kernel 3: mean(log(rowsum)) ---------------------------------
__global__ void finalize(const float* __restrict__ rowsum, float* __restrict__ out) {
    float s = 0.f;
    for (int i = threadIdx.x; i < NN; i += 256)
        s += __builtin_amdgcn_logf(rowsum[i]) * 0.69314718056f;
#pragma unroll
    for (int o = 1; o < 64; o <<= 1)
        s += __shfl_xor(s, o);
    __shared__ float wsum[4];
    if ((threadIdx.x & 63) == 0) wsum[threadIdx.x >> 6] = s;
    __syncthreads();
    if (threadIdx.x == 0)
        out[0] = (wsum[0] + wsum[1] + wsum[2] + wsum[3]) * (1.0f / NN);
}

extern "C" void kernel_launch(void* const* d_in, const int* in_sizes, int n_in,
                              void* d_out, int out_size, void* d_ws, size_t ws_size,
                              hipStream_t stream) {
    const float* x = (const float*)d_in[0];
    float* out = (float*)d_out;

    ushort* xb    = (ushort*)d_ws;                               // 4 MB bf16, swizzled
    float* rowsum = (float*)((char*)d_ws + (size_t)NN * DD * 2); // 64 KB

    hipMemsetAsync(rowsum, 0, NN * sizeof(float), stream);
    convert_swz<<<(NN * 16) / 256, 256, 0, stream>>>(x, xb);
    gemm_exp_sym<<<NBLK, 512, 0, stream>>>(xb, rowsum);
    finalize<<<1, 256, 0, stream>>>(rowsum, out);
}

// Round 3
// 88.504 us; speedup vs baseline: 2.2079x; 1.9956x over previous
//
#include <hip/hip_runtime.h>
#include <hip/hip_bf16.h>

#define NN 16384
#define DD 128
#define NBLOCKS 512          // 128 row-strips x 4 col-quarters
#define TILES 32             // 4096 cols / 128 per tile
#define SQRT_SCALE 4.5398159622f   // sqrt(log2(e)/0.07); dot in xb-units == exp2 arg

typedef __attribute__((ext_vector_type(8))) short bf16x8;
typedef __attribute__((ext_vector_type(4))) float f32x4;

// ---------------- Kernel 1: fp32 -> scaled bf16, swizzled layout ---------------
// 16B chunk c of row r stored at chunk position (c ^ (r&15)). Linear global->LDS
// staging then yields a tile whose ds_read_b128 pattern is bank-uniform.
__global__ void convert_swz(const float* __restrict__ x, ushort* __restrict__ xb) {
    int t = blockIdx.x * blockDim.x + threadIdx.x;   // one thread per 8-elem chunk
    int r = t >> 4;
    int c = t & 15;
    const float4* src = (const float4*)(x + (size_t)r * DD + c * 8);
    float4 f0 = src[0];
    float4 f1 = src[1];
    float vals[8] = {f0.x, f0.y, f0.z, f0.w, f1.x, f1.y, f1.z, f1.w};
    bf16x8 v;
#pragma unroll
    for (int i = 0; i < 8; ++i) {
        __hip_bfloat16 h = __float2bfloat16(vals[i] * SQRT_SCALE);
        v[i] = (short)__builtin_bit_cast(unsigned short, h);
    }
    int cs = c ^ (r & 15);
    *(bf16x8*)(xb + (size_t)r * DD + cs * 8) = v;
}

// ---------------- Kernel 2: streaming X·X^T -> exp2 -> register row-sums -------
// Block owns 128 rows x 4096 cols. A-fragments in registers for the whole
// kernel; B tiles (128 rows of xb = cols of sims) double-buffered in LDS via
// global_load_lds with counted vmcnt. Row sums accumulate in registers; one
// cross-lane reduce + direct store at the end. No atomics.
__global__ __launch_bounds__(256, 2) void gemm_exp_stream(const ushort* __restrict__ xb,
                                                          float* __restrict__ rowsumP) {
    __shared__ __align__(16) ushort lB[2][128 * DD];   // 2 x 32 KB

    const int tid  = threadIdx.x;
    const int lane = tid & 63;
    const int wid  = tid >> 6;       // 0..3
    const int frow = lane & 15;
    const int kq   = lane >> 4;

    // XCD-aware bijective swizzle: 512 = 8 * 64
    const int bid = blockIdx.x;
    const int swz = (bid & 7) * 64 + (bid >> 3);
    const int rstrip = swz >> 2;     // 0..127
    const int cq     = swz & 3;      // 0..3
    const int rw = wid >> 1;         // wave row-half (0..1)
    const int cw = wid & 1;          // wave col-half (0..1)
    const int R0 = rstrip * 128;
    const int C0 = cq * 4096;

    // ---- A fragments: 64 rows per wave, full K=128, in registers forever ----
    bf16x8 af[4][4];                 // [m][kk]
#pragma unroll
    for (int m = 0; m < 4; ++m)
#pragma unroll
        for (int kk = 0; kk < 4; ++kk) {
            int ra = R0 + rw * 64 + m * 16 + frow;
            int slot = (kk * 4 + kq) ^ frow;     // ra&15 == frow
            af[m][kk] = *(const bf16x8*)(xb + (size_t)ra * DD + slot * 8);
        }

    // ---- precomputed LDS byte offsets for B-fragment reads ----
    int boff[16];
#pragma unroll
    for (int n = 0; n < 4; ++n)
#pragma unroll
        for (int kk = 0; kk < 4; ++kk) {
            int rb = cw * 64 + n * 16 + frow;
            int slot = (kk * 4 + kq) ^ frow;     // rb&15 == frow
            boff[n * 4 + kk] = rb * 256 + slot * 16;
        }

    // Drain A loads so vmcnt bookkeeping below counts only staging loads.
    asm volatile("s_waitcnt vmcnt(0)" ::: "memory");

    auto stage = [&](int buf, int t) {
        const char* g = (const char*)(xb + (size_t)(C0 + t * 128) * DD);
#pragma unroll
        for (int i = 0; i < 8; ++i) {
            int off = (wid * 8 + i) * 1024;
            __builtin_amdgcn_global_load_lds(
                (const __attribute__((address_space(1))) unsigned int*)(g + off + lane * 16),
                (__attribute__((address_space(3))) unsigned int*)((char*)&lB[buf][0] + off),
                16, 0, 0);
        }
    };

    stage(0, 0);

    f32x4 acc[4][4];
#pragma unroll
    for (int m = 0; m < 4; ++m)
#pragma unroll
        for (int n = 0; n < 4; ++n)
            acc[m][n] = (f32x4){0.f, 0.f, 0.f, 0.f};
    float rs[4][4] = {};

    for (int t = 0; t < TILES; ++t) {
        const int cur = t & 1;
        if (t < TILES - 1) {
            stage(cur ^ 1, t + 1);
            asm volatile("s_waitcnt vmcnt(8)" ::: "memory");   // tile t landed
        } else {
            asm volatile("s_waitcnt vmcnt(0)" ::: "memory");
        }
        __builtin_amdgcn_s_barrier();

        const char* Bb = (const char*)&lB[cur][0];
#pragma unroll
        for (int kk = 0; kk < 4; ++kk) {
            bf16x8 bfr[4];
#pragma unroll
            for (int n = 0; n < 4; ++n)
                bfr[n] = *(const bf16x8*)(Bb + boff[n * 4 + kk]);
#pragma unroll
            for (int m = 0; m < 4; ++m)
#pragma unroll
                for (int n = 0; n < 4; ++n)
                    acc[m][n] = __builtin_amdgcn_mfma_f32_16x16x32_bf16(af[m][kk], bfr[n],
                                                                        acc[m][n], 0, 0, 0);
        }
        __builtin_amdgcn_s_barrier();   // all reads of lB[cur] consumed

        // Register-only epilogue (overlaps other waves' staging/wait).
        // acc is already the exp2 argument (scale baked into xb).
#pragma unroll
        for (int m = 0; m < 4; ++m)
#pragma unroll
            for (int j = 0; j < 4; ++j) {
                float s = __builtin_amdgcn_exp2f(acc[m][0][j])
                        + __builtin_amdgcn_exp2f(acc[m][1][j])
                        + __builtin_amdgcn_exp2f(acc[m][2][j])
                        + __builtin_amdgcn_exp2f(acc[m][3][j]);
                rs[m][j] += s;
            }
#pragma unroll
        for (int m = 0; m < 4; ++m)
#pragma unroll
            for (int n = 0; n < 4; ++n)
                acc[m][n] = (f32x4){0.f, 0.f, 0.f, 0.f};
    }

    // ---- once-per-kernel cross-lane reduce over the 16 col-lanes ----
#pragma unroll
    for (int m = 0; m < 4; ++m)
#pragma unroll
        for (int j = 0; j < 4; ++j) {
            float s = rs[m][j];
            s += __shfl_xor(s, 1);
            s += __shfl_xor(s, 2);
            s += __shfl_xor(s, 4);
            s += __shfl_xor(s, 8);
            rs[m][j] = s;
        }
    if (frow == 0) {
        const int p = cq * 2 + cw;           // partial slot 0..7
        float* dst = rowsumP + (size_t)p * NN + R0 + rw * 64 + kq * 4;
#pragma unroll
        for (int m = 0; m < 4; ++m) {
            float4 v = {rs[m][0], rs[m][1], rs[m][2], rs[m][3]};
            *(float4*)(dst + m * 16) = v;    // row = R0+rw*64+m*16+kq*4+j
        }
    }
}

// ---------------- Kernel 3: mean(log(sum of 8 partials)) ----------------------
__global__ void finalize(const float* __restrict__ rowsumP, float* __restrict__ out) {
    const int tid = threadIdx.x;   // 1024 threads
    float s = 0.f;
    for (int i = tid; i < NN; i += 1024) {
        float r = 0.f;
#pragma unroll
        for (int p = 0; p < 8; ++p)
            r += rowsumP[p * NN + i];
        s += __builtin_amdgcn_logf(r) * 0.69314718056f;
    }
#pragma unroll
    for (int o = 1; o < 64; o <<= 1)
        s += __shfl_xor(s, o);
    __shared__ float wsum[16];
    if ((tid & 63) == 0) wsum[tid >> 6] = s;
    __syncthreads();
    if (tid == 0) {
        float tot = 0.f;
#pragma unroll
        for (int w = 0; w < 16; ++w) tot += wsum[w];
        out[0] = tot * (1.0f / NN);
    }
}

extern "C" void kernel_launch(void* const* d_in, const int* in_sizes, int n_in,
                              void* d_out, int out_size, void* d_ws, size_t ws_size,
                              hipStream_t stream) {
    const float* x = (const float*)d_in[0];
    float* out = (float*)d_out;

    ushort* xb      = (ushort*)d_ws;                               // 4 MB scaled bf16
    float* rowsumP  = (float*)((char*)d_ws + (size_t)NN * DD * 2); // 8 x 64 KB partials

    convert_swz<<<(NN * 16) / 256, 256, 0, stream>>>(x, xb);
    gemm_exp_stream<<<NBLOCKS, 256, 0, stream>>>(xb, rowsumP);
    finalize<<<1, 1024, 0, stream>>>(rowsumP, out);
}